// Round 13
// baseline (157.621 us; speedup 1.0000x reference)
//
#include <hip/hip_runtime.h>
#include <hip/hip_fp16.h>

#define N_NODES 10000
#define BATCH 8
#define FIN 128
#define UNITS 32
#define NH1 4
#define MAXDEG 128

#define WAVE_FENCE() asm volatile("s_waitcnt lgkmcnt(0)" ::: "memory")

#define FMA_MIX_LO(acc, u, a) \
    asm("v_fma_mix_f32 %0, %1, %2, %0 op_sel:[0,0,0] op_sel_hi:[1,0,0]" \
        : "+v"(acc) : "v"(u), "v"(a))
#define FMA_MIX_HI(acc, u, a) \
    asm("v_fma_mix_f32 %0, %1, %2, %0 op_sel:[1,0,0] op_sel_hi:[1,0,0]" \
        : "+v"(acc) : "v"(u), "v"(a))

typedef _Float16 half8 __attribute__((ext_vector_type(8)));
typedef float f32x4 __attribute__((ext_vector_type(4)));

// ---------------- build (padded buckets) + prep (Wt1/Wt2/wa2), one kernel ----------
// blocks [0,EB): adjacency build; blocks [EB, EB+97): weight prep.
__global__ void build_prep_kernel(const int* __restrict__ esrc, const int* __restrict__ edst,
                                  int* __restrict__ deg, int* __restrict__ colPad, int E, int EB,
                                  const float* __restrict__ W1, const float* __restrict__ a1s,
                                  const float* __restrict__ a1d, const float* __restrict__ W2,
                                  const float* __restrict__ a2s, const float* __restrict__ a2d,
                                  __half* __restrict__ Wt1, __half* __restrict__ Wt2,
                                  float* __restrict__ wa2) {
    int blk = blockIdx.x;
    if (blk < EB) {
        int e = blk * 256 + threadIdx.x;
        if (e < E) {
            int d = edst[e];
            int pos = atomicAdd(&deg[d], 1);
            colPad[(d << 7) + pos] = esrc[e];
        }
        return;
    }
    int t = (blk - EB) * 256 + threadIdx.x;
    const int NP1 = 144 * 128;           // Wt1[c][k]
    const int NP2 = 48 * 128;            // Wt2[c][k]
    if (t < NP1) {
        int c = t >> 7, k = t & 127;
        float v = 0.f;
        if (c < 128) v = W1[k * 128 + c];
        else if (c < 132) {
            int h = c - 128;
            for (int u = 0; u < 32; ++u) v += W1[k * 128 + h * 32 + u] * a1s[h * 32 + u];
        } else if (c < 136) {
            int h = c - 132;
            for (int u = 0; u < 32; ++u) v += W1[k * 128 + h * 32 + u] * a1d[h * 32 + u];
        }
        Wt1[t] = __float2half(v);
    } else if (t < NP1 + NP2) {
        int q = t - NP1;
        int c = q >> 7, k = q & 127;
        float v = (c < 32) ? W2[k * 32 + c] : 0.f;
        Wt2[q] = __float2half(v);
    } else if (t < NP1 + NP2 + 256) {
        int c = t - NP1 - NP2;           // wa2[0..127]=W2·a2s, [128..255]=W2·a2d
        int k = c & 127;
        const float* a = (c < 128) ? a2s : a2d;
        float v = 0.f;
        for (int u = 0; u < 32; ++u) v += W2[k * 32 + u] * a[u];
        wa2[c] = v;
    }
}

// ---------------- MFMA GEMM + optional fused logit tile ----------------
// D[row][col] = X[row][:]·Wt[col][:]. 256 thr = 4 waves x 16 rows. K=128.
template<typename XT, int NTILES, int HTILES, int ES>
__global__ __launch_bounds__(256)
void gemm_mfma(const XT* __restrict__ X, const __half* __restrict__ Wt,
               __half* __restrict__ Hout, float* __restrict__ es,
               float* __restrict__ ed, int rows) {
    constexpr int K = 128;
    constexpr int HCOLS = HTILES * 16;
    constexpr int PAD = 136;
    __shared__ _Float16 Wl[NTILES * 16][PAD];
    const int tid = threadIdx.x;
    for (int idx = tid; idx < NTILES * 16 * K / 8; idx += 256) {
        int r = idx >> 4, kq = idx & 15;
        *(half8*)&Wl[r][kq * 8] = *(const half8*)(Wt + r * K + kq * 8);
    }
    __syncthreads();
    const int w = tid >> 6, lane = tid & 63;
    const int row16 = blockIdx.x * 64 + w * 16;
    const int arow = row16 + (lane & 15);
    const int cl = lane & 15;
    f32x4 acc[NTILES] = {};
    #pragma unroll
    for (int kb = 0; kb < 4; ++kb) {
        int kbase = kb * 32 + ((lane >> 4) << 3);
        half8 a;
        if constexpr (sizeof(XT) == 4) {
            const float* xp = (const float*)X + (size_t)arow * K + kbase;
            float4 v0 = *(const float4*)xp;
            float4 v1 = *(const float4*)(xp + 4);
            a[0] = v0.x; a[1] = v0.y; a[2] = v0.z; a[3] = v0.w;
            a[4] = v1.x; a[5] = v1.y; a[6] = v1.z; a[7] = v1.w;
        } else {
            a = *(const half8*)((const _Float16*)X + (size_t)arow * K + kbase);
        }
        #pragma unroll
        for (int t = 0; t < NTILES; ++t) {
            half8 b = *(const half8*)&Wl[t * 16 + cl][kbase];
            acc[t] = __builtin_amdgcn_mfma_f32_16x16x32_f16(a, b, acc[t], 0, 0, 0);
        }
    }
    const int rbase = row16 + ((lane >> 4) << 2);
    #pragma unroll
    for (int t = 0; t < HTILES; ++t) {
        #pragma unroll
        for (int i = 0; i < 4; ++i)
            Hout[(size_t)(rbase + i) * HCOLS + t * 16 + cl] = __float2half(acc[t][i]);
    }
    if constexpr (ES > 0) {
        f32x4 lg = acc[HTILES];
        if (cl < ES) {
            #pragma unroll
            for (int i = 0; i < 4; ++i) es[(size_t)(rbase + i) * ES + cl] = lg[i];
        } else if (cl < 2 * ES) {
            #pragma unroll
            for (int i = 0; i < 4; ++i) ed[(size_t)(rbase + i) * ES + (cl - ES)] = lg[i];
        }
    }
}

// ---------------- layer-1 aggregation + fused layer-2 logits ----------------
__global__ __launch_bounds__(512)
void agg1_kernel(const int* __restrict__ deg, const int* __restrict__ colPad,
                 const float* __restrict__ es, const float* __restrict__ ed,
                 const __half* __restrict__ Hf, const float* __restrict__ bias,
                 const float* __restrict__ wa2, __half* __restrict__ outH,
                 float* __restrict__ e2s, float* __restrict__ e2d) {
    __shared__ float evS[8][MAXDEG][4];
    __shared__ int colS[8][MAXDEG];      // byte offsets (s*256)
    int blk = blockIdx.x;
    int b = blk & 7;                     // batch -> XCD
    int grp = blk >> 3;
    int w = threadIdx.x >> 6;
    int d = grp * 8 + w;
    int lane = threadIdx.x & 63;
    int eg = lane >> 4;
    int c8 = lane & 15;
    int head = c8 >> 2;
    int n = deg[d];
    const int* colp = colPad + (d << 7);
    size_t brow = (size_t)b * N_NODES;
    size_t drow = brow + d;
    float4 ed4 = ((const float4*)ed)[drow];
    float dx = 0.f, dy = 0.f, dz = 0.f, dw = 0.f;
    #pragma unroll
    for (int rep = 0; rep < 2; ++rep) {
        int i = lane + rep * 64;
        if (i < n) {
            int s = colp[i];
            colS[w][i] = s << 8;         // byte offset into 256-B rows
            float4 e4 = ((const float4*)es)[brow + s];
            float l, a0, a1, a2, a3;
            l = e4.x + ed4.x; l = l > 0.f ? l : 0.2f * l; a0 = __expf(l); dx += a0;
            l = e4.y + ed4.y; l = l > 0.f ? l : 0.2f * l; a1 = __expf(l); dy += a1;
            l = e4.z + ed4.z; l = l > 0.f ? l : 0.2f * l; a2 = __expf(l); dz += a2;
            l = e4.w + ed4.w; l = l > 0.f ? l : 0.2f * l; a3 = __expf(l); dw += a3;
            *(float4*)&evS[w][i][0] = make_float4(a0, a1, a2, a3);
        }
    }
    WAVE_FENCE();
    float acc[8] = {};
    const char* hbase = (const char*)Hf + (brow << 8) + (c8 << 4);
    int n16 = n & ~15;
    for (int t = 0; t < n16; t += 16) {
        int t0 = t + eg, t1 = t0 + 4, t2 = t0 + 8, t3 = t0 + 12;
        float a0 = evS[w][t0][head], a1 = evS[w][t1][head];
        float a2 = evS[w][t2][head], a3 = evS[w][t3][head];
        int o0 = colS[w][t0], o1 = colS[w][t1], o2 = colS[w][t2], o3 = colS[w][t3];
        float4 r0 = *(const float4*)(hbase + o0);
        float4 r1 = *(const float4*)(hbase + o1);
        float4 r2 = *(const float4*)(hbase + o2);
        float4 r3 = *(const float4*)(hbase + o3);
        const unsigned* u0 = (const unsigned*)&r0;
        const unsigned* u1 = (const unsigned*)&r1;
        const unsigned* u2 = (const unsigned*)&r2;
        const unsigned* u3 = (const unsigned*)&r3;
        #pragma unroll
        for (int j = 0; j < 4; ++j) {
            FMA_MIX_LO(acc[2 * j],     u0[j], a0);
            FMA_MIX_HI(acc[2 * j + 1], u0[j], a0);
        }
        #pragma unroll
        for (int j = 0; j < 4; ++j) {
            FMA_MIX_LO(acc[2 * j],     u1[j], a1);
            FMA_MIX_HI(acc[2 * j + 1], u1[j], a1);
        }
        #pragma unroll
        for (int j = 0; j < 4; ++j) {
            FMA_MIX_LO(acc[2 * j],     u2[j], a2);
            FMA_MIX_HI(acc[2 * j + 1], u2[j], a2);
        }
        #pragma unroll
        for (int j = 0; j < 4; ++j) {
            FMA_MIX_LO(acc[2 * j],     u3[j], a3);
            FMA_MIX_HI(acc[2 * j + 1], u3[j], a3);
        }
    }
    for (int t = n16; t < n; t += 4) {
        int myt = t + eg;
        int tt = myt < n ? myt : 0;
        float a = evS[w][tt][head]; if (myt >= n) a = 0.f;
        int o = colS[w][tt];
        float4 r = *(const float4*)(hbase + o);
        const unsigned* u = (const unsigned*)&r;
        #pragma unroll
        for (int j = 0; j < 4; ++j) {
            FMA_MIX_LO(acc[2 * j],     u[j], a);
            FMA_MIX_HI(acc[2 * j + 1], u[j], a);
        }
    }
    #pragma unroll
    for (int off = 32; off; off >>= 1) {
        dx += __shfl_xor(dx, off);
        dy += __shfl_xor(dy, off);
        dz += __shfl_xor(dz, off);
        dw += __shfl_xor(dw, off);
    }
    float ix = 1.f / (dx + 1e-9f);
    float iy = 1.f / (dy + 1e-9f);
    float iz = 1.f / (dz + 1e-9f);
    float iw = 1.f / (dw + 1e-9f);
    float inv = (head & 2) ? ((head & 1) ? iw : iz) : ((head & 1) ? iy : ix);
    #pragma unroll
    for (int j = 0; j < 8; ++j) {
        acc[j] += __shfl_xor(acc[j], 16);
        acc[j] += __shfl_xor(acc[j], 32);
    }
    if (eg == 0) {
        float4 b0 = *(const float4*)(bias + 8 * c8);
        float4 b1 = *(const float4*)(bias + 8 * c8 + 4);
        float vals[8];
        vals[0] = fmaxf(acc[0] * inv + b0.x, 0.f);
        vals[1] = fmaxf(acc[1] * inv + b0.y, 0.f);
        vals[2] = fmaxf(acc[2] * inv + b0.z, 0.f);
        vals[3] = fmaxf(acc[3] * inv + b0.w, 0.f);
        vals[4] = fmaxf(acc[4] * inv + b1.x, 0.f);
        vals[5] = fmaxf(acc[5] * inv + b1.y, 0.f);
        vals[6] = fmaxf(acc[6] * inv + b1.z, 0.f);
        vals[7] = fmaxf(acc[7] * inv + b1.w, 0.f);
        __half2 o[4];
        #pragma unroll
        for (int j = 0; j < 4; ++j) o[j] = __floats2half2_rn(vals[2 * j], vals[2 * j + 1]);
        *(float4*)(outH + drow * 128 + c8 * 8) = *(float4*)o;
        // fused layer-2 logits: e2 = out1row · (W2·a2)
        const float* w2s = wa2 + 8 * c8;
        const float* w2d = wa2 + 128 + 8 * c8;
        float es2 = vals[0] * w2s[0] + vals[1] * w2s[1] + vals[2] * w2s[2] + vals[3] * w2s[3]
                  + vals[4] * w2s[4] + vals[5] * w2s[5] + vals[6] * w2s[6] + vals[7] * w2s[7];
        float ed2 = vals[0] * w2d[0] + vals[1] * w2d[1] + vals[2] * w2d[2] + vals[3] * w2d[3]
                  + vals[4] * w2d[4] + vals[5] * w2d[5] + vals[6] * w2d[6] + vals[7] * w2d[7];
        es2 += __shfl_xor(es2, 1); es2 += __shfl_xor(es2, 2);
        es2 += __shfl_xor(es2, 4); es2 += __shfl_xor(es2, 8);
        ed2 += __shfl_xor(ed2, 1); ed2 += __shfl_xor(ed2, 2);
        ed2 += __shfl_xor(ed2, 4); ed2 += __shfl_xor(ed2, 8);
        if (c8 == 0) {
            e2s[drow] = es2;
            e2d[drow] = ed2;
        }
    }
}

// ---------------- layer-2 aggregation ----------------
__global__ __launch_bounds__(512)
void agg2_kernel(const int* __restrict__ deg, const int* __restrict__ colPad,
                 const float* __restrict__ es, const float* __restrict__ ed,
                 const __half* __restrict__ Hf, const float* __restrict__ bias,
                 float* __restrict__ outF) {
    __shared__ float evS[8][MAXDEG];
    __shared__ int colS[8][MAXDEG];      // byte offsets (s*64)
    int blk = blockIdx.x;
    int b = blk & 7;
    int grp = blk >> 3;
    int w = threadIdx.x >> 6;
    int d = grp * 8 + w;
    int lane = threadIdx.x & 63;
    int eg = lane >> 2;
    int c8 = lane & 3;
    int n = deg[d];
    const int* colp = colPad + (d << 7);
    size_t brow = (size_t)b * N_NODES;
    size_t drow = brow + d;
    float edv = ed[drow];
    float den = 0.f;
    #pragma unroll
    for (int rep = 0; rep < 2; ++rep) {
        int i = lane + rep * 64;
        if (i < n) {
            int s = colp[i];
            colS[w][i] = s << 6;
            float l = es[brow + s] + edv;
            l = l > 0.f ? l : 0.2f * l;
            float ev = __expf(l);
            den += ev;
            evS[w][i] = ev;
        }
    }
    WAVE_FENCE();
    float acc[8] = {};
    const char* hbase = (const char*)Hf + (brow << 6) + (c8 << 4);
    int n32 = n & ~31;
    for (int t = 0; t < n32; t += 32) {
        int t0 = t + eg, t1 = t0 + 16;
        float a0 = evS[w][t0];
        float a1 = evS[w][t1];
        int o0 = colS[w][t0];
        int o1 = colS[w][t1];
        float4 r0 = *(const float4*)(hbase + o0);
        float4 r1 = *(const float4*)(hbase + o1);
        const unsigned* u0 = (const unsigned*)&r0;
        const unsigned* u1 = (const unsigned*)&r1;
        #pragma unroll
        for (int j = 0; j < 4; ++j) {
            FMA_MIX_LO(acc[2 * j],     u0[j], a0);
            FMA_MIX_HI(acc[2 * j + 1], u0[j], a0);
        }
        #pragma unroll
        for (int j = 0; j < 4; ++j) {
            FMA_MIX_LO(acc[2 * j],     u1[j], a1);
            FMA_MIX_HI(acc[2 * j + 1], u1[j], a1);
        }
    }
    for (int t = n32; t < n; t += 16) {
        int myt = t + eg;
        int tt = myt < n ? myt : 0;
        float a = evS[w][tt]; if (myt >= n) a = 0.f;
        int o = colS[w][tt];
        float4 r = *(const float4*)(hbase + o);
        const unsigned* u = (const unsigned*)&r;
        #pragma unroll
        for (int j = 0; j < 4; ++j) {
            FMA_MIX_LO(acc[2 * j],     u[j], a);
            FMA_MIX_HI(acc[2 * j + 1], u[j], a);
        }
    }
    #pragma unroll
    for (int off = 32; off; off >>= 1) den += __shfl_xor(den, off);
    float inv = 1.f / (den + 1e-9f);
    #pragma unroll
    for (int j = 0; j < 8; ++j) {
        acc[j] += __shfl_xor(acc[j], 4);
        acc[j] += __shfl_xor(acc[j], 8);
        acc[j] += __shfl_xor(acc[j], 16);
        acc[j] += __shfl_xor(acc[j], 32);
    }
    if (eg == 0) {
        float4 b0 = *(const float4*)(bias + 8 * c8);
        float4 b1 = *(const float4*)(bias + 8 * c8 + 4);
        float4 o0, o1;
        o0.x = acc[0] * inv + b0.x;
        o0.y = acc[1] * inv + b0.y;
        o0.z = acc[2] * inv + b0.z;
        o0.w = acc[3] * inv + b0.w;
        o1.x = acc[4] * inv + b1.x;
        o1.y = acc[5] * inv + b1.y;
        o1.z = acc[6] * inv + b1.z;
        o1.w = acc[7] * inv + b1.w;
        float* op = outF + drow * 32 + 8 * c8;
        *(float4*)op = o0;
        *(float4*)(op + 4) = o1;
    }
}

extern "C" void kernel_launch(void* const* d_in, const int* in_sizes, int n_in,
                              void* d_out, int out_size, void* d_ws, size_t ws_size,
                              hipStream_t stream) {
    const float* x    = (const float*)d_in[0];
    const int*   esrc = (const int*)d_in[1];
    const int*   edst = (const int*)d_in[2];
    const float* W1   = (const float*)d_in[3];
    const float* a1s  = (const float*)d_in[4];
    const float* a1d  = (const float*)d_in[5];
    const float* b1   = (const float*)d_in[6];
    const float* W2   = (const float*)d_in[7];
    const float* a2s  = (const float*)d_in[8];
    const float* a2d  = (const float*)d_in[9];
    const float* b2   = (const float*)d_in[10];
    float* out = (float*)d_out;
    const int E = in_sizes[1];
    const int rows = BATCH * N_NODES;  // 80000

    // workspace layout
    float* wsf = (float*)d_ws;
    __half* h1h   = (__half*)wsf;                       // rows*128 halfs
    float*  e1s   = wsf + (size_t)rows * 64;            // rows*4
    float*  e1d   = e1s + (size_t)rows * 4;             // rows*4
    __half* out1h = (__half*)(e1d + (size_t)rows * 4);  // rows*128 halfs
    int* deg      = (int*)((float*)out1h + (size_t)rows * 64);  // N
    int* colPad   = deg + N_NODES;                      // N*128
    __half* Wt1   = (__half*)(colPad + N_NODES * 128);  // 144*128 halfs
    __half* Wt2   = Wt1 + 144 * 128;                    // 48*128 halfs
    float* wa2    = (float*)(Wt2 + 48 * 128);           // 256
    float* e2s    = wa2 + 256;                          // rows
    float* e2d    = e2s + rows;                         // rows
    __half* h2h   = h1h;                                // reuse (h1h dead after agg1)

    const int TPB = 256;
    const int EB = (E + TPB - 1) / TPB;
    const int PREPB = (144 * 128 + 48 * 128 + 256 + TPB - 1) / TPB;

    // ---------- adjacency + weight prep (one kernel) ----------
    hipMemsetAsync(deg, 0, N_NODES * sizeof(int), stream);
    build_prep_kernel<<<EB + PREPB, TPB, 0, stream>>>(
        esrc, edst, deg, colPad, E, EB, W1, a1s, a1d, W2, a2s, a2d, Wt1, Wt2, wa2);

    // ---------- layer 1 ----------
    gemm_mfma<float, 9, 8, 4><<<rows / 64, 256, 0, stream>>>(
        x, Wt1, h1h, e1s, e1d, rows);
    agg1_kernel<<<(N_NODES / 8) * BATCH, 512, 0, stream>>>(
        deg, colPad, e1s, e1d, h1h, b1, wa2, out1h, e2s, e2d);

    // ---------- layer 2 ----------
    gemm_mfma<__half, 2, 2, 0><<<rows / 64, 256, 0, stream>>>(
        out1h, Wt2, h2h, nullptr, nullptr, rows);
    agg2_kernel<<<(N_NODES / 8) * BATCH, 512, 0, stream>>>(
        deg, colPad, e2s, e2d, h2h, b2, out);
}

// Round 14
// 149.521 us; speedup vs baseline: 1.0542x; 1.0542x over previous
//
#include <hip/hip_runtime.h>
#include <hip/hip_fp16.h>

#define N_NODES 10000
#define BATCH 8
#define FIN 128
#define UNITS 32
#define NH1 4
#define MAXDEG 128

#define WAVE_FENCE() asm volatile("s_waitcnt lgkmcnt(0)" ::: "memory")

#define FMA_MIX_LO(acc, u, a) \
    asm("v_fma_mix_f32 %0, %1, %2, %0 op_sel:[0,0,0] op_sel_hi:[1,0,0]" \
        : "+v"(acc) : "v"(u), "v"(a))
#define FMA_MIX_HI(acc, u, a) \
    asm("v_fma_mix_f32 %0, %1, %2, %0 op_sel:[1,0,0] op_sel_hi:[1,0,0]" \
        : "+v"(acc) : "v"(u), "v"(a))

typedef _Float16 half8 __attribute__((ext_vector_type(8)));
typedef float f32x4 __attribute__((ext_vector_type(4)));

// ---------------- build (padded buckets) + prep (Wt1/Wt2), one kernel ----------
__global__ void build_prep_kernel(const int* __restrict__ esrc, const int* __restrict__ edst,
                                  int* __restrict__ deg, int* __restrict__ colPad, int E, int EB,
                                  const float* __restrict__ W1, const float* __restrict__ a1s,
                                  const float* __restrict__ a1d, const float* __restrict__ W2,
                                  const float* __restrict__ a2s, const float* __restrict__ a2d,
                                  __half* __restrict__ Wt1, __half* __restrict__ Wt2) {
    int blk = blockIdx.x;
    if (blk < EB) {
        int e = blk * 256 + threadIdx.x;
        if (e < E) {
            int d = edst[e];
            int pos = atomicAdd(&deg[d], 1);
            colPad[(d << 7) + pos] = esrc[e];
        }
        return;
    }
    int t = (blk - EB) * 256 + threadIdx.x;
    const int NP1 = 144 * 128;           // Wt1[c][k]
    if (t < NP1) {
        int c = t >> 7, k = t & 127;
        float v = 0.f;
        if (c < 128) v = W1[k * 128 + c];
        else if (c < 132) {
            int h = c - 128;
            for (int u = 0; u < 32; ++u) v += W1[k * 128 + h * 32 + u] * a1s[h * 32 + u];
        } else if (c < 136) {
            int h = c - 132;
            for (int u = 0; u < 32; ++u) v += W1[k * 128 + h * 32 + u] * a1d[h * 32 + u];
        }
        Wt1[t] = __float2half(v);
    } else if (t < NP1 + 48 * 128) {
        int q = t - NP1;
        int c = q >> 7, k = q & 127;
        float v = 0.f;
        if (c < 32) v = W2[k * 32 + c];
        else if (c == 32) { for (int u = 0; u < 32; ++u) v += W2[k * 32 + u] * a2s[u]; }
        else if (c == 33) { for (int u = 0; u < 32; ++u) v += W2[k * 32 + u] * a2d[u]; }
        Wt2[q] = __float2half(v);
    }
}

// ---------------- MFMA GEMM + fused logit tile (round-12 verbatim) ----------------
template<typename XT, int NTILES, int HTILES, int ES>
__global__ __launch_bounds__(256)
void gemm_mfma(const XT* __restrict__ X, const __half* __restrict__ Wt,
               __half* __restrict__ Hout, float* __restrict__ es,
               float* __restrict__ ed, int rows) {
    constexpr int K = 128;
    constexpr int HCOLS = HTILES * 16;
    constexpr int PAD = 136;
    __shared__ _Float16 Wl[NTILES * 16][PAD];
    const int tid = threadIdx.x;
    for (int idx = tid; idx < NTILES * 16 * K / 8; idx += 256) {
        int r = idx >> 4, kq = idx & 15;
        *(half8*)&Wl[r][kq * 8] = *(const half8*)(Wt + r * K + kq * 8);
    }
    __syncthreads();
    const int w = tid >> 6, lane = tid & 63;
    const int row16 = blockIdx.x * 64 + w * 16;
    const int arow = row16 + (lane & 15);
    const int cl = lane & 15;
    f32x4 acc[NTILES] = {};
    #pragma unroll
    for (int kb = 0; kb < 4; ++kb) {
        int kbase = kb * 32 + ((lane >> 4) << 3);
        half8 a;
        if constexpr (sizeof(XT) == 4) {
            const float* xp = (const float*)X + (size_t)arow * K + kbase;
            float4 v0 = *(const float4*)xp;
            float4 v1 = *(const float4*)(xp + 4);
            a[0] = v0.x; a[1] = v0.y; a[2] = v0.z; a[3] = v0.w;
            a[4] = v1.x; a[5] = v1.y; a[6] = v1.z; a[7] = v1.w;
        } else {
            a = *(const half8*)((const _Float16*)X + (size_t)arow * K + kbase);
        }
        #pragma unroll
        for (int t = 0; t < NTILES; ++t) {
            half8 b = *(const half8*)&Wl[t * 16 + cl][kbase];
            acc[t] = __builtin_amdgcn_mfma_f32_16x16x32_f16(a, b, acc[t], 0, 0, 0);
        }
    }
    const int rbase = row16 + ((lane >> 4) << 2);
    #pragma unroll
    for (int t = 0; t < HTILES; ++t) {
        #pragma unroll
        for (int i = 0; i < 4; ++i)
            Hout[(size_t)(rbase + i) * HCOLS + t * 16 + cl] = __float2half(acc[t][i]);
    }
    if constexpr (ES > 0) {
        f32x4 lg = acc[HTILES];
        if (cl < ES) {
            #pragma unroll
            for (int i = 0; i < 4; ++i) es[(size_t)(rbase + i) * ES + cl] = lg[i];
        } else if (cl < 2 * ES) {
            #pragma unroll
            for (int i = 0; i < 4; ++i) ed[(size_t)(rbase + i) * ES + (cl - ES)] = lg[i];
        }
    }
}

// ---------------- layer-1 aggregation (round-12 body + zero-padded tail) ----------
__global__ __launch_bounds__(512)
void agg1_kernel(const int* __restrict__ deg, const int* __restrict__ colPad,
                 const float* __restrict__ es, const float* __restrict__ ed,
                 const __half* __restrict__ Hf, const float* __restrict__ bias,
                 __half* __restrict__ outH) {
    __shared__ float evS[8][MAXDEG][4];
    __shared__ int colS[8][MAXDEG];
    int blk = blockIdx.x;
    int b = blk & 7;                  // batch -> XCD
    int grp = blk >> 3;
    int w = threadIdx.x >> 6;
    int d = grp * 8 + w;
    int lane = threadIdx.x & 63;
    int eg = lane >> 4;
    int c8 = lane & 15;
    int head = c8 >> 2;
    int n = deg[d];
    const int* colp = colPad + (d << 7);
    size_t brow = (size_t)b * N_NODES;
    size_t drow = brow + d;
    float4 ed4 = ((const float4*)ed)[drow];
    float dx = 0.f, dy = 0.f, dz = 0.f, dw = 0.f;
    // phase 1: alphas; pad slots up to the next multiple of 16 get alpha=0, col=0
    #pragma unroll
    for (int rep = 0; rep < 2; ++rep) {
        int i = lane + rep * 64;
        float4 av = make_float4(0.f, 0.f, 0.f, 0.f);
        int sv = 0;
        if (i < n) {
            sv = colp[i];
            float4 e4 = ((const float4*)es)[brow + sv];
            float l, a0, a1, a2, a3;
            l = e4.x + ed4.x; l = l > 0.f ? l : 0.2f * l; a0 = __expf(l); dx += a0;
            l = e4.y + ed4.y; l = l > 0.f ? l : 0.2f * l; a1 = __expf(l); dy += a1;
            l = e4.z + ed4.z; l = l > 0.f ? l : 0.2f * l; a2 = __expf(l); dz += a2;
            l = e4.w + ed4.w; l = l > 0.f ? l : 0.2f * l; a3 = __expf(l); dw += a3;
            av = make_float4(a0, a1, a2, a3);
        }
        *(float4*)&evS[w][i][0] = av;
        colS[w][i] = sv;
    }
    WAVE_FENCE();
    // phase 2: fully guard-free ILP-4 accumulate over padded count
    float acc[8] = {};
    const __half* hbase = Hf + (brow << 7) + (c8 << 3);
    int nR = (n + 15) & ~15;
    for (int t = 0; t < nR; t += 16) {
        int t0 = t + eg, t1 = t0 + 4, t2 = t0 + 8, t3 = t0 + 12;
        float a0 = evS[w][t0][head], a1 = evS[w][t1][head];
        float a2 = evS[w][t2][head], a3 = evS[w][t3][head];
        int s0 = colS[w][t0], s1 = colS[w][t1], s2 = colS[w][t2], s3 = colS[w][t3];
        float4 r0 = *(const float4*)(hbase + ((size_t)s0 << 7));
        float4 r1 = *(const float4*)(hbase + ((size_t)s1 << 7));
        float4 r2 = *(const float4*)(hbase + ((size_t)s2 << 7));
        float4 r3 = *(const float4*)(hbase + ((size_t)s3 << 7));
        const unsigned* u0 = (const unsigned*)&r0;
        const unsigned* u1 = (const unsigned*)&r1;
        const unsigned* u2 = (const unsigned*)&r2;
        const unsigned* u3 = (const unsigned*)&r3;
        #pragma unroll
        for (int j = 0; j < 4; ++j) {
            FMA_MIX_LO(acc[2 * j],     u0[j], a0);
            FMA_MIX_HI(acc[2 * j + 1], u0[j], a0);
        }
        #pragma unroll
        for (int j = 0; j < 4; ++j) {
            FMA_MIX_LO(acc[2 * j],     u1[j], a1);
            FMA_MIX_HI(acc[2 * j + 1], u1[j], a1);
        }
        #pragma unroll
        for (int j = 0; j < 4; ++j) {
            FMA_MIX_LO(acc[2 * j],     u2[j], a2);
            FMA_MIX_HI(acc[2 * j + 1], u2[j], a2);
        }
        #pragma unroll
        for (int j = 0; j < 4; ++j) {
            FMA_MIX_LO(acc[2 * j],     u3[j], a3);
            FMA_MIX_HI(acc[2 * j + 1], u3[j], a3);
        }
    }
    #pragma unroll
    for (int off = 32; off; off >>= 1) {
        dx += __shfl_xor(dx, off);
        dy += __shfl_xor(dy, off);
        dz += __shfl_xor(dz, off);
        dw += __shfl_xor(dw, off);
    }
    float ix = 1.f / (dx + 1e-9f);
    float iy = 1.f / (dy + 1e-9f);
    float iz = 1.f / (dz + 1e-9f);
    float iw = 1.f / (dw + 1e-9f);
    float inv = (head & 2) ? ((head & 1) ? iw : iz) : ((head & 1) ? iy : ix);
    #pragma unroll
    for (int j = 0; j < 8; ++j) {
        acc[j] += __shfl_xor(acc[j], 16);
        acc[j] += __shfl_xor(acc[j], 32);
    }
    if (eg == 0) {
        float4 b0 = *(const float4*)(bias + 8 * c8);
        float4 b1 = *(const float4*)(bias + 8 * c8 + 4);
        float vals[8];
        vals[0] = fmaxf(acc[0] * inv + b0.x, 0.f);
        vals[1] = fmaxf(acc[1] * inv + b0.y, 0.f);
        vals[2] = fmaxf(acc[2] * inv + b0.z, 0.f);
        vals[3] = fmaxf(acc[3] * inv + b0.w, 0.f);
        vals[4] = fmaxf(acc[4] * inv + b1.x, 0.f);
        vals[5] = fmaxf(acc[5] * inv + b1.y, 0.f);
        vals[6] = fmaxf(acc[6] * inv + b1.z, 0.f);
        vals[7] = fmaxf(acc[7] * inv + b1.w, 0.f);
        __half2 o[4];
        #pragma unroll
        for (int j = 0; j < 4; ++j) o[j] = __floats2half2_rn(vals[2 * j], vals[2 * j + 1]);
        *(float4*)(outH + drow * 128 + c8 * 8) = *(float4*)o;
    }
}

// ---------------- layer-2 aggregation (round-12 body + zero-padded tail) ----------
__global__ __launch_bounds__(512)
void agg2_kernel(const int* __restrict__ deg, const int* __restrict__ colPad,
                 const float* __restrict__ es, const float* __restrict__ ed,
                 const __half* __restrict__ Hf, const float* __restrict__ bias,
                 float* __restrict__ outF) {
    __shared__ float evS[8][MAXDEG];
    __shared__ int colS[8][MAXDEG];
    int blk = blockIdx.x;
    int b = blk & 7;
    int grp = blk >> 3;
    int w = threadIdx.x >> 6;
    int d = grp * 8 + w;
    int lane = threadIdx.x & 63;
    int eg = lane >> 2;
    int c8 = lane & 3;
    int n = deg[d];
    const int* colp = colPad + (d << 7);
    size_t brow = (size_t)b * N_NODES;
    size_t drow = brow + d;
    float edv = ed[drow];
    float den = 0.f;
    #pragma unroll
    for (int rep = 0; rep < 2; ++rep) {
        int i = lane + rep * 64;
        float av = 0.f;
        int sv = 0;
        if (i < n) {
            sv = colp[i];
            float l = es[brow + sv] + edv;
            l = l > 0.f ? l : 0.2f * l;
            av = __expf(l);
            den += av;
        }
        evS[w][i] = av;
        colS[w][i] = sv;
    }
    WAVE_FENCE();
    float acc[8] = {};
    const __half* hbase = Hf + (brow << 5) + (c8 << 3);
    int nR = (n + 31) & ~31;
    for (int t = 0; t < nR; t += 32) {
        int t0 = t + eg, t1 = t0 + 16;
        float a0 = evS[w][t0];
        float a1 = evS[w][t1];
        int s0 = colS[w][t0];
        int s1 = colS[w][t1];
        float4 r0 = *(const float4*)(hbase + ((size_t)s0 << 5));
        float4 r1 = *(const float4*)(hbase + ((size_t)s1 << 5));
        const unsigned* u0 = (const unsigned*)&r0;
        const unsigned* u1 = (const unsigned*)&r1;
        #pragma unroll
        for (int j = 0; j < 4; ++j) {
            FMA_MIX_LO(acc[2 * j],     u0[j], a0);
            FMA_MIX_HI(acc[2 * j + 1], u0[j], a0);
        }
        #pragma unroll
        for (int j = 0; j < 4; ++j) {
            FMA_MIX_LO(acc[2 * j],     u1[j], a1);
            FMA_MIX_HI(acc[2 * j + 1], u1[j], a1);
        }
    }
    #pragma unroll
    for (int off = 32; off; off >>= 1) den += __shfl_xor(den, off);
    float inv = 1.f / (den + 1e-9f);
    #pragma unroll
    for (int j = 0; j < 8; ++j) {
        acc[j] += __shfl_xor(acc[j], 4);
        acc[j] += __shfl_xor(acc[j], 8);
        acc[j] += __shfl_xor(acc[j], 16);
        acc[j] += __shfl_xor(acc[j], 32);
    }
    if (eg == 0) {
        float4 b0 = *(const float4*)(bias + 8 * c8);
        float4 b1 = *(const float4*)(bias + 8 * c8 + 4);
        float4 o0, o1;
        o0.x = acc[0] * inv + b0.x;
        o0.y = acc[1] * inv + b0.y;
        o0.z = acc[2] * inv + b0.z;
        o0.w = acc[3] * inv + b0.w;
        o1.x = acc[4] * inv + b1.x;
        o1.y = acc[5] * inv + b1.y;
        o1.z = acc[6] * inv + b1.z;
        o1.w = acc[7] * inv + b1.w;
        float* op = outF + drow * 32 + 8 * c8;
        *(float4*)op = o0;
        *(float4*)(op + 4) = o1;
    }
}

extern "C" void kernel_launch(void* const* d_in, const int* in_sizes, int n_in,
                              void* d_out, int out_size, void* d_ws, size_t ws_size,
                              hipStream_t stream) {
    const float* x    = (const float*)d_in[0];
    const int*   esrc = (const int*)d_in[1];
    const int*   edst = (const int*)d_in[2];
    const float* W1   = (const float*)d_in[3];
    const float* a1s  = (const float*)d_in[4];
    const float* a1d  = (const float*)d_in[5];
    const float* b1   = (const float*)d_in[6];
    const float* W2   = (const float*)d_in[7];
    const float* a2s  = (const float*)d_in[8];
    const float* a2d  = (const float*)d_in[9];
    const float* b2   = (const float*)d_in[10];
    float* out = (float*)d_out;
    const int E = in_sizes[1];
    const int rows = BATCH * N_NODES;  // 80000

    // workspace layout (round-12)
    float* wsf = (float*)d_ws;
    __half* h1h   = (__half*)wsf;                       // rows*128 halfs
    float*  e1s   = wsf + (size_t)rows * 64;            // rows*4
    float*  e1d   = e1s + (size_t)rows * 4;             // rows*4
    __half* out1h = (__half*)(e1d + (size_t)rows * 4);  // rows*128 halfs
    int* deg      = (int*)((float*)out1h + (size_t)rows * 64);  // N
    int* colPad   = deg + N_NODES;                      // N*128
    __half* Wt1   = (__half*)(colPad + N_NODES * 128);  // 144*128 halfs
    __half* Wt2   = Wt1 + 144 * 128;                    // 48*128 halfs
    // layer 2 reuse
    __half* h2h = h1h;
    float*  e2s = e1s;
    float*  e2d = e1s + rows;

    const int TPB = 256;
    const int EB = (E + TPB - 1) / TPB;
    const int PREPB = (144 * 128 + 48 * 128 + TPB - 1) / TPB;

    // ---------- adjacency + weight prep (one kernel) ----------
    hipMemsetAsync(deg, 0, N_NODES * sizeof(int), stream);
    build_prep_kernel<<<EB + PREPB, TPB, 0, stream>>>(
        esrc, edst, deg, colPad, E, EB, W1, a1s, a1d, W2, a2s, a2d, Wt1, Wt2);

    // ---------- layer 1 ----------
    gemm_mfma<float, 9, 8, 4><<<rows / 64, 256, 0, stream>>>(
        x, Wt1, h1h, e1s, e1d, rows);
    agg1_kernel<<<(N_NODES / 8) * BATCH, 512, 0, stream>>>(
        deg, colPad, e1s, e1d, h1h, b1, out1h);

    // ---------- layer 2 ----------
    gemm_mfma<__half, 3, 2, 1><<<rows / 64, 256, 0, stream>>>(
        out1h, Wt2, h2h, e2s, e2d, rows);
    agg2_kernel<<<(N_NODES / 8) * BATCH, 512, 0, stream>>>(
        deg, colPad, e2s, e2d, h2h, b2, out);
}

// Round 15
// 142.478 us; speedup vs baseline: 1.1063x; 1.0494x over previous
//
#include <hip/hip_runtime.h>
#include <hip/hip_fp16.h>

#define N_NODES 10000
#define BATCH 8
#define FIN 128
#define UNITS 32
#define NH1 4
#define MAXDEG 128

#define WAVE_FENCE() asm volatile("s_waitcnt lgkmcnt(0)" ::: "memory")

#define FMA_MIX_LO(acc, u, a) \
    asm("v_fma_mix_f32 %0, %1, %2, %0 op_sel:[0,0,0] op_sel_hi:[1,0,0]" \
        : "+v"(acc) : "v"(u), "v"(a))
#define FMA_MIX_HI(acc, u, a) \
    asm("v_fma_mix_f32 %0, %1, %2, %0 op_sel:[1,0,0] op_sel_hi:[1,0,0]" \
        : "+v"(acc) : "v"(u), "v"(a))

typedef _Float16 half8 __attribute__((ext_vector_type(8)));
typedef float f32x4 __attribute__((ext_vector_type(4)));

// ---------------- prep: deg zeroing + Wt1/Wt2 build (one launch, no memset) -------
__global__ void prep_kernel(int ZB, int* __restrict__ deg,
                            const float* __restrict__ W1, const float* __restrict__ a1s,
                            const float* __restrict__ a1d, const float* __restrict__ W2,
                            const float* __restrict__ a2s, const float* __restrict__ a2d,
                            __half* __restrict__ Wt1, __half* __restrict__ Wt2) {
    int blk = blockIdx.x;
    if (blk < ZB) {
        int i = blk * 256 + threadIdx.x;
        if (i < N_NODES) deg[i] = 0;
        return;
    }
    int t = (blk - ZB) * 256 + threadIdx.x;
    const int NP1 = 144 * 128;           // Wt1[c][k]
    if (t < NP1) {
        int c = t >> 7, k = t & 127;
        float v = 0.f;
        if (c < 128) v = W1[k * 128 + c];
        else if (c < 132) {
            int h = c - 128;
            for (int u = 0; u < 32; ++u) v += W1[k * 128 + h * 32 + u] * a1s[h * 32 + u];
        } else if (c < 136) {
            int h = c - 132;
            for (int u = 0; u < 32; ++u) v += W1[k * 128 + h * 32 + u] * a1d[h * 32 + u];
        }
        Wt1[t] = __float2half(v);
    } else if (t < NP1 + 48 * 128) {
        int q = t - NP1;
        int c = q >> 7, k = q & 127;
        float v = 0.f;
        if (c < 32) v = W2[k * 32 + c];
        else if (c == 32) { for (int u = 0; u < 32; ++u) v += W2[k * 32 + u] * a2s[u]; }
        else if (c == 33) { for (int u = 0; u < 32; ++u) v += W2[k * 32 + u] * a2d[u]; }
        Wt2[q] = __float2half(v);
    }
}

// ---------------- MFMA GEMM body (r14 verbatim, blk passed in) ----------------
template<typename XT, int NTILES, int HTILES, int ES>
__device__ __forceinline__
void gemm_body(int blk, const XT* __restrict__ X, const __half* __restrict__ Wt,
               __half* __restrict__ Hout, float* __restrict__ es,
               float* __restrict__ ed, int rows) {
    constexpr int K = 128;
    constexpr int HCOLS = HTILES * 16;
    constexpr int PAD = 136;
    __shared__ _Float16 Wl[NTILES * 16][PAD];
    const int tid = threadIdx.x;
    for (int idx = tid; idx < NTILES * 16 * K / 8; idx += 256) {
        int r = idx >> 4, kq = idx & 15;
        *(half8*)&Wl[r][kq * 8] = *(const half8*)(Wt + r * K + kq * 8);
    }
    __syncthreads();
    const int w = tid >> 6, lane = tid & 63;
    const int row16 = blk * 64 + w * 16;
    const int arow = row16 + (lane & 15);
    const int cl = lane & 15;
    f32x4 acc[NTILES] = {};
    #pragma unroll
    for (int kb = 0; kb < 4; ++kb) {
        int kbase = kb * 32 + ((lane >> 4) << 3);
        half8 a;
        if constexpr (sizeof(XT) == 4) {
            const float* xp = (const float*)X + (size_t)arow * K + kbase;
            float4 v0 = *(const float4*)xp;
            float4 v1 = *(const float4*)(xp + 4);
            a[0] = v0.x; a[1] = v0.y; a[2] = v0.z; a[3] = v0.w;
            a[4] = v1.x; a[5] = v1.y; a[6] = v1.z; a[7] = v1.w;
        } else {
            a = *(const half8*)((const _Float16*)X + (size_t)arow * K + kbase);
        }
        #pragma unroll
        for (int t = 0; t < NTILES; ++t) {
            half8 b = *(const half8*)&Wl[t * 16 + cl][kbase];
            acc[t] = __builtin_amdgcn_mfma_f32_16x16x32_f16(a, b, acc[t], 0, 0, 0);
        }
    }
    const int rbase = row16 + ((lane >> 4) << 2);
    #pragma unroll
    for (int t = 0; t < HTILES; ++t) {
        #pragma unroll
        for (int i = 0; i < 4; ++i)
            Hout[(size_t)(rbase + i) * HCOLS + t * 16 + cl] = __float2half(acc[t][i]);
    }
    if constexpr (ES > 0) {
        f32x4 lg = acc[HTILES];
        if (cl < ES) {
            #pragma unroll
            for (int i = 0; i < 4; ++i) es[(size_t)(rbase + i) * ES + cl] = lg[i];
        } else if (cl < 2 * ES) {
            #pragma unroll
            for (int i = 0; i < 4; ++i) ed[(size_t)(rbase + i) * ES + (cl - ES)] = lg[i];
        }
    }
}

// ---------------- layer-1 GEMM + edge-bucket build merged in one launch ----------
// blocks [0,G1): gemm; [G1, G1+EB): adjacency build (independent work, hides under MFMA)
__global__ __launch_bounds__(256)
void gemm1_build(const float* __restrict__ X, const __half* __restrict__ Wt,
                 __half* __restrict__ Hout, float* __restrict__ es,
                 float* __restrict__ ed, int rows, int G1,
                 const int* __restrict__ esrc, const int* __restrict__ edst,
                 int* __restrict__ deg, int* __restrict__ colPad, int E) {
    int blk = blockIdx.x;
    if (blk >= G1) {
        int e = (blk - G1) * 256 + threadIdx.x;
        if (e < E) {
            int d = edst[e];
            int pos = atomicAdd(&deg[d], 1);
            colPad[(d << 7) + pos] = esrc[e];
        }
        return;
    }
    gemm_body<float, 9, 8, 4>(blk, X, Wt, Hout, es, ed, rows);
}

// ---------------- layer-2 GEMM ----------------
__global__ __launch_bounds__(256)
void gemm2_kernel(const __half* __restrict__ X, const __half* __restrict__ Wt,
                  __half* __restrict__ Hout, float* __restrict__ es,
                  float* __restrict__ ed, int rows) {
    gemm_body<__half, 3, 2, 1>(blockIdx.x, X, Wt, Hout, es, ed, rows);
}

// ---------------- layer-1 aggregation (r14 verbatim) ----------------
__global__ __launch_bounds__(512)
void agg1_kernel(const int* __restrict__ deg, const int* __restrict__ colPad,
                 const float* __restrict__ es, const float* __restrict__ ed,
                 const __half* __restrict__ Hf, const float* __restrict__ bias,
                 __half* __restrict__ outH) {
    __shared__ float evS[8][MAXDEG][4];
    __shared__ int colS[8][MAXDEG];
    int blk = blockIdx.x;
    int b = blk & 7;                  // batch -> XCD
    int grp = blk >> 3;
    int w = threadIdx.x >> 6;
    int d = grp * 8 + w;
    int lane = threadIdx.x & 63;
    int eg = lane >> 4;
    int c8 = lane & 15;
    int head = c8 >> 2;
    int n = deg[d];
    const int* colp = colPad + (d << 7);
    size_t brow = (size_t)b * N_NODES;
    size_t drow = brow + d;
    float4 ed4 = ((const float4*)ed)[drow];
    float dx = 0.f, dy = 0.f, dz = 0.f, dw = 0.f;
    #pragma unroll
    for (int rep = 0; rep < 2; ++rep) {
        int i = lane + rep * 64;
        float4 av = make_float4(0.f, 0.f, 0.f, 0.f);
        int sv = 0;
        if (i < n) {
            sv = colp[i];
            float4 e4 = ((const float4*)es)[brow + sv];
            float l, a0, a1, a2, a3;
            l = e4.x + ed4.x; l = l > 0.f ? l : 0.2f * l; a0 = __expf(l); dx += a0;
            l = e4.y + ed4.y; l = l > 0.f ? l : 0.2f * l; a1 = __expf(l); dy += a1;
            l = e4.z + ed4.z; l = l > 0.f ? l : 0.2f * l; a2 = __expf(l); dz += a2;
            l = e4.w + ed4.w; l = l > 0.f ? l : 0.2f * l; a3 = __expf(l); dw += a3;
            av = make_float4(a0, a1, a2, a3);
        }
        *(float4*)&evS[w][i][0] = av;
        colS[w][i] = sv;
    }
    WAVE_FENCE();
    float acc[8] = {};
    const __half* hbase = Hf + (brow << 7) + (c8 << 3);
    int nR = (n + 15) & ~15;
    for (int t = 0; t < nR; t += 16) {
        int t0 = t + eg, t1 = t0 + 4, t2 = t0 + 8, t3 = t0 + 12;
        float a0 = evS[w][t0][head], a1 = evS[w][t1][head];
        float a2 = evS[w][t2][head], a3 = evS[w][t3][head];
        int s0 = colS[w][t0], s1 = colS[w][t1], s2 = colS[w][t2], s3 = colS[w][t3];
        float4 r0 = *(const float4*)(hbase + ((size_t)s0 << 7));
        float4 r1 = *(const float4*)(hbase + ((size_t)s1 << 7));
        float4 r2 = *(const float4*)(hbase + ((size_t)s2 << 7));
        float4 r3 = *(const float4*)(hbase + ((size_t)s3 << 7));
        const unsigned* u0 = (const unsigned*)&r0;
        const unsigned* u1 = (const unsigned*)&r1;
        const unsigned* u2 = (const unsigned*)&r2;
        const unsigned* u3 = (const unsigned*)&r3;
        #pragma unroll
        for (int j = 0; j < 4; ++j) {
            FMA_MIX_LO(acc[2 * j],     u0[j], a0);
            FMA_MIX_HI(acc[2 * j + 1], u0[j], a0);
        }
        #pragma unroll
        for (int j = 0; j < 4; ++j) {
            FMA_MIX_LO(acc[2 * j],     u1[j], a1);
            FMA_MIX_HI(acc[2 * j + 1], u1[j], a1);
        }
        #pragma unroll
        for (int j = 0; j < 4; ++j) {
            FMA_MIX_LO(acc[2 * j],     u2[j], a2);
            FMA_MIX_HI(acc[2 * j + 1], u2[j], a2);
        }
        #pragma unroll
        for (int j = 0; j < 4; ++j) {
            FMA_MIX_LO(acc[2 * j],     u3[j], a3);
            FMA_MIX_HI(acc[2 * j + 1], u3[j], a3);
        }
    }
    #pragma unroll
    for (int off = 32; off; off >>= 1) {
        dx += __shfl_xor(dx, off);
        dy += __shfl_xor(dy, off);
        dz += __shfl_xor(dz, off);
        dw += __shfl_xor(dw, off);
    }
    float ix = 1.f / (dx + 1e-9f);
    float iy = 1.f / (dy + 1e-9f);
    float iz = 1.f / (dz + 1e-9f);
    float iw = 1.f / (dw + 1e-9f);
    float inv = (head & 2) ? ((head & 1) ? iw : iz) : ((head & 1) ? iy : ix);
    #pragma unroll
    for (int j = 0; j < 8; ++j) {
        acc[j] += __shfl_xor(acc[j], 16);
        acc[j] += __shfl_xor(acc[j], 32);
    }
    if (eg == 0) {
        float4 b0 = *(const float4*)(bias + 8 * c8);
        float4 b1 = *(const float4*)(bias + 8 * c8 + 4);
        float vals[8];
        vals[0] = fmaxf(acc[0] * inv + b0.x, 0.f);
        vals[1] = fmaxf(acc[1] * inv + b0.y, 0.f);
        vals[2] = fmaxf(acc[2] * inv + b0.z, 0.f);
        vals[3] = fmaxf(acc[3] * inv + b0.w, 0.f);
        vals[4] = fmaxf(acc[4] * inv + b1.x, 0.f);
        vals[5] = fmaxf(acc[5] * inv + b1.y, 0.f);
        vals[6] = fmaxf(acc[6] * inv + b1.z, 0.f);
        vals[7] = fmaxf(acc[7] * inv + b1.w, 0.f);
        __half2 o[4];
        #pragma unroll
        for (int j = 0; j < 4; ++j) o[j] = __floats2half2_rn(vals[2 * j], vals[2 * j + 1]);
        *(float4*)(outH + drow * 128 + c8 * 8) = *(float4*)o;
    }
}

// ---------------- layer-2 aggregation (r14 verbatim) ----------------
__global__ __launch_bounds__(512)
void agg2_kernel(const int* __restrict__ deg, const int* __restrict__ colPad,
                 const float* __restrict__ es, const float* __restrict__ ed,
                 const __half* __restrict__ Hf, const float* __restrict__ bias,
                 float* __restrict__ outF) {
    __shared__ float evS[8][MAXDEG];
    __shared__ int colS[8][MAXDEG];
    int blk = blockIdx.x;
    int b = blk & 7;
    int grp = blk >> 3;
    int w = threadIdx.x >> 6;
    int d = grp * 8 + w;
    int lane = threadIdx.x & 63;
    int eg = lane >> 2;
    int c8 = lane & 3;
    int n = deg[d];
    const int* colp = colPad + (d << 7);
    size_t brow = (size_t)b * N_NODES;
    size_t drow = brow + d;
    float edv = ed[drow];
    float den = 0.f;
    #pragma unroll
    for (int rep = 0; rep < 2; ++rep) {
        int i = lane + rep * 64;
        float av = 0.f;
        int sv = 0;
        if (i < n) {
            sv = colp[i];
            float l = es[brow + sv] + edv;
            l = l > 0.f ? l : 0.2f * l;
            av = __expf(l);
            den += av;
        }
        evS[w][i] = av;
        colS[w][i] = sv;
    }
    WAVE_FENCE();
    float acc[8] = {};
    const __half* hbase = Hf + (brow << 5) + (c8 << 3);
    int nR = (n + 31) & ~31;
    for (int t = 0; t < nR; t += 32) {
        int t0 = t + eg, t1 = t0 + 16;
        float a0 = evS[w][t0];
        float a1 = evS[w][t1];
        int s0 = colS[w][t0];
        int s1 = colS[w][t1];
        float4 r0 = *(const float4*)(hbase + ((size_t)s0 << 5));
        float4 r1 = *(const float4*)(hbase + ((size_t)s1 << 5));
        const unsigned* u0 = (const unsigned*)&r0;
        const unsigned* u1 = (const unsigned*)&r1;
        #pragma unroll
        for (int j = 0; j < 4; ++j) {
            FMA_MIX_LO(acc[2 * j],     u0[j], a0);
            FMA_MIX_HI(acc[2 * j + 1], u0[j], a0);
        }
        #pragma unroll
        for (int j = 0; j < 4; ++j) {
            FMA_MIX_LO(acc[2 * j],     u1[j], a1);
            FMA_MIX_HI(acc[2 * j + 1], u1[j], a1);
        }
    }
    #pragma unroll
    for (int off = 32; off; off >>= 1) den += __shfl_xor(den, off);
    float inv = 1.f / (den + 1e-9f);
    #pragma unroll
    for (int j = 0; j < 8; ++j) {
        acc[j] += __shfl_xor(acc[j], 4);
        acc[j] += __shfl_xor(acc[j], 8);
        acc[j] += __shfl_xor(acc[j], 16);
        acc[j] += __shfl_xor(acc[j], 32);
    }
    if (eg == 0) {
        float4 b0 = *(const float4*)(bias + 8 * c8);
        float4 b1 = *(const float4*)(bias + 8 * c8 + 4);
        float4 o0, o1;
        o0.x = acc[0] * inv + b0.x;
        o0.y = acc[1] * inv + b0.y;
        o0.z = acc[2] * inv + b0.z;
        o0.w = acc[3] * inv + b0.w;
        o1.x = acc[4] * inv + b1.x;
        o1.y = acc[5] * inv + b1.y;
        o1.z = acc[6] * inv + b1.z;
        o1.w = acc[7] * inv + b1.w;
        float* op = outF + drow * 32 + 8 * c8;
        *(float4*)op = o0;
        *(float4*)(op + 4) = o1;
    }
}

extern "C" void kernel_launch(void* const* d_in, const int* in_sizes, int n_in,
                              void* d_out, int out_size, void* d_ws, size_t ws_size,
                              hipStream_t stream) {
    const float* x    = (const float*)d_in[0];
    const int*   esrc = (const int*)d_in[1];
    const int*   edst = (const int*)d_in[2];
    const float* W1   = (const float*)d_in[3];
    const float* a1s  = (const float*)d_in[4];
    const float* a1d  = (const float*)d_in[5];
    const float* b1   = (const float*)d_in[6];
    const float* W2   = (const float*)d_in[7];
    const float* a2s  = (const float*)d_in[8];
    const float* a2d  = (const float*)d_in[9];
    const float* b2   = (const float*)d_in[10];
    float* out = (float*)d_out;
    const int E = in_sizes[1];
    const int rows = BATCH * N_NODES;  // 80000

    // workspace layout
    float* wsf = (float*)d_ws;
    __half* h1h   = (__half*)wsf;                       // rows*128 halfs
    float*  e1s   = wsf + (size_t)rows * 64;            // rows*4
    float*  e1d   = e1s + (size_t)rows * 4;             // rows*4
    __half* out1h = (__half*)(e1d + (size_t)rows * 4);  // rows*128 halfs
    int* deg      = (int*)((float*)out1h + (size_t)rows * 64);  // N
    int* colPad   = deg + N_NODES;                      // N*128
    __half* Wt1   = (__half*)(colPad + N_NODES * 128);  // 144*128 halfs
    __half* Wt2   = Wt1 + 144 * 128;                    // 48*128 halfs
    // layer 2 reuse
    __half* h2h = h1h;
    float*  e2s = e1s;
    float*  e2d = e1s + rows;

    const int TPB = 256;
    const int ZB = (N_NODES + TPB - 1) / TPB;                       // deg-zero blocks
    const int PREPB = (144 * 128 + 48 * 128 + TPB - 1) / TPB;       // weight-prep blocks
    const int G1 = rows / 64;                                       // gemm1 blocks
    const int EB = (E + TPB - 1) / TPB;                             // build blocks

    // ---------- 1: deg zero + weight prep ----------
    prep_kernel<<<ZB + PREPB, TPB, 0, stream>>>(
        ZB, deg, W1, a1s, a1d, W2, a2s, a2d, Wt1, Wt2);

    // ---------- 2: layer-1 GEMM (+logits) with edge-bucket build hidden under it --
    gemm1_build<<<G1 + EB, TPB, 0, stream>>>(
        x, Wt1, h1h, e1s, e1d, rows, G1, esrc, edst, deg, colPad, E);

    // ---------- 3: layer-1 aggregation ----------
    agg1_kernel<<<(N_NODES / 8) * BATCH, 512, 0, stream>>>(
        deg, colPad, e1s, e1d, h1h, b1, out1h);

    // ---------- 4: layer-2 GEMM (+logits) ----------
    gemm2_kernel<<<rows / 64, TPB, 0, stream>>>(
        out1h, Wt2, h2h, e2s, e2d, rows);

    // ---------- 5: layer-2 aggregation ----------
    agg2_kernel<<<(N_NODES / 8) * BATCH, 512, 0, stream>>>(
        deg, colPad, e2s, e2d, h2h, b2, out);
}

// Round 16
// 140.535 us; speedup vs baseline: 1.1216x; 1.0138x over previous
//
#include <hip/hip_runtime.h>
#include <hip/hip_fp16.h>

#define N_NODES 10000
#define BATCH 8
#define FIN 128
#define UNITS 32
#define NH1 4
#define MAXDEG 128
#define LOG2E 1.44269504f

#define WAVE_FENCE() asm volatile("s_waitcnt lgkmcnt(0)" ::: "memory")

#define FMA_MIX_LO(acc, u, a) \
    asm("v_fma_mix_f32 %0, %1, %2, %0 op_sel:[0,0,0] op_sel_hi:[1,0,0]" \
        : "+v"(acc) : "v"(u), "v"(a))
#define FMA_MIX_HI(acc, u, a) \
    asm("v_fma_mix_f32 %0, %1, %2, %0 op_sel:[1,0,0] op_sel_hi:[1,0,0]" \
        : "+v"(acc) : "v"(u), "v"(a))
// 2^x in one VALU instruction (logits pre-scaled by log2(e) in prep)
#define EXP2(dst, src) asm("v_exp_f32 %0, %1" : "=v"(dst) : "v"(src))

typedef _Float16 half8 __attribute__((ext_vector_type(8)));
typedef float f32x4 __attribute__((ext_vector_type(4)));

// ---------------- prep: deg zeroing + Wt1/Wt2 build (logit cols pre-scaled) -------
__global__ void prep_kernel(int ZB, int* __restrict__ deg,
                            const float* __restrict__ W1, const float* __restrict__ a1s,
                            const float* __restrict__ a1d, const float* __restrict__ W2,
                            const float* __restrict__ a2s, const float* __restrict__ a2d,
                            __half* __restrict__ Wt1, __half* __restrict__ Wt2) {
    int blk = blockIdx.x;
    if (blk < ZB) {
        int i = blk * 256 + threadIdx.x;
        if (i < N_NODES) deg[i] = 0;
        return;
    }
    int t = (blk - ZB) * 256 + threadIdx.x;
    const int NP1 = 144 * 128;           // Wt1[c][k]
    if (t < NP1) {
        int c = t >> 7, k = t & 127;
        float v = 0.f;
        if (c < 128) v = W1[k * 128 + c];
        else if (c < 132) {
            int h = c - 128;
            for (int u = 0; u < 32; ++u) v += W1[k * 128 + h * 32 + u] * a1s[h * 32 + u];
            v *= LOG2E;
        } else if (c < 136) {
            int h = c - 132;
            for (int u = 0; u < 32; ++u) v += W1[k * 128 + h * 32 + u] * a1d[h * 32 + u];
            v *= LOG2E;
        }
        Wt1[t] = __float2half(v);
    } else if (t < NP1 + 48 * 128) {
        int q = t - NP1;
        int c = q >> 7, k = q & 127;
        float v = 0.f;
        if (c < 32) v = W2[k * 32 + c];
        else if (c == 32) { for (int u = 0; u < 32; ++u) v += W2[k * 32 + u] * a2s[u]; v *= LOG2E; }
        else if (c == 33) { for (int u = 0; u < 32; ++u) v += W2[k * 32 + u] * a2d[u]; v *= LOG2E; }
        Wt2[q] = __float2half(v);
    }
}

// ---------------- MFMA GEMM body ----------------
template<typename XT, int NTILES, int HTILES, int ES>
__device__ __forceinline__
void gemm_body(int blk, const XT* __restrict__ X, const __half* __restrict__ Wt,
               __half* __restrict__ Hout, float* __restrict__ es,
               float* __restrict__ ed, int rows) {
    constexpr int K = 128;
    constexpr int HCOLS = HTILES * 16;
    constexpr int PAD = 136;
    __shared__ _Float16 Wl[NTILES * 16][PAD];
    const int tid = threadIdx.x;
    for (int idx = tid; idx < NTILES * 16 * K / 8; idx += 256) {
        int r = idx >> 4, kq = idx & 15;
        *(half8*)&Wl[r][kq * 8] = *(const half8*)(Wt + r * K + kq * 8);
    }
    __syncthreads();
    const int w = tid >> 6, lane = tid & 63;
    const int row16 = blk * 64 + w * 16;
    const int arow = row16 + (lane & 15);
    const int cl = lane & 15;
    f32x4 acc[NTILES] = {};
    #pragma unroll
    for (int kb = 0; kb < 4; ++kb) {
        int kbase = kb * 32 + ((lane >> 4) << 3);
        half8 a;
        if constexpr (sizeof(XT) == 4) {
            const float* xp = (const float*)X + (size_t)arow * K + kbase;
            float4 v0 = *(const float4*)xp;
            float4 v1 = *(const float4*)(xp + 4);
            a[0] = v0.x; a[1] = v0.y; a[2] = v0.z; a[3] = v0.w;
            a[4] = v1.x; a[5] = v1.y; a[6] = v1.z; a[7] = v1.w;
        } else {
            a = *(const half8*)((const _Float16*)X + (size_t)arow * K + kbase);
        }
        #pragma unroll
        for (int t = 0; t < NTILES; ++t) {
            half8 b = *(const half8*)&Wl[t * 16 + cl][kbase];
            acc[t] = __builtin_amdgcn_mfma_f32_16x16x32_f16(a, b, acc[t], 0, 0, 0);
        }
    }
    const int rbase = row16 + ((lane >> 4) << 2);
    #pragma unroll
    for (int t = 0; t < HTILES; ++t) {
        #pragma unroll
        for (int i = 0; i < 4; ++i)
            Hout[(size_t)(rbase + i) * HCOLS + t * 16 + cl] = __float2half(acc[t][i]);
    }
    if constexpr (ES > 0) {
        f32x4 lg = acc[HTILES];
        if (cl < ES) {
            #pragma unroll
            for (int i = 0; i < 4; ++i) es[(size_t)(rbase + i) * ES + cl] = lg[i];
        } else if (cl < 2 * ES) {
            #pragma unroll
            for (int i = 0; i < 4; ++i) ed[(size_t)(rbase + i) * ES + (cl - ES)] = lg[i];
        }
    }
}

// ---------------- layer-1 GEMM + edge-bucket build merged ----------
__global__ __launch_bounds__(256)
void gemm1_build(const float* __restrict__ X, const __half* __restrict__ Wt,
                 __half* __restrict__ Hout, float* __restrict__ es,
                 float* __restrict__ ed, int rows, int G1,
                 const int* __restrict__ esrc, const int* __restrict__ edst,
                 int* __restrict__ deg, int* __restrict__ colPad, int E) {
    int blk = blockIdx.x;
    if (blk >= G1) {
        int e = (blk - G1) * 256 + threadIdx.x;
        if (e < E) {
            int d = edst[e];
            int pos = atomicAdd(&deg[d], 1);
            colPad[(d << 7) + pos] = esrc[e];
        }
        return;
    }
    gemm_body<float, 9, 8, 4>(blk, X, Wt, Hout, es, ed, rows);
}

// ---------------- layer-2 GEMM ----------------
__global__ __launch_bounds__(256)
void gemm2_kernel(const __half* __restrict__ X, const __half* __restrict__ Wt,
                  __half* __restrict__ Hout, float* __restrict__ es,
                  float* __restrict__ ed, int rows) {
    gemm_body<__half, 3, 2, 1>(blockIdx.x, X, Wt, Hout, es, ed, rows);
}

// ---------------- layer-1 aggregation (rep-2 branch + exp2) ----------------
__global__ __launch_bounds__(512)
void agg1_kernel(const int* __restrict__ deg, const int* __restrict__ colPad,
                 const float* __restrict__ es, const float* __restrict__ ed,
                 const __half* __restrict__ Hf, const float* __restrict__ bias,
                 __half* __restrict__ outH) {
    __shared__ float evS[8][MAXDEG][4];
    __shared__ int colS[8][MAXDEG];
    int blk = blockIdx.x;
    int b = blk & 7;                  // batch -> XCD
    int grp = blk >> 3;
    int w = threadIdx.x >> 6;
    int d = grp * 8 + w;
    int lane = threadIdx.x & 63;
    int eg = lane >> 4;
    int c8 = lane & 15;
    int head = c8 >> 2;
    int n = deg[d];
    const int* colp = colPad + (d << 7);
    size_t brow = (size_t)b * N_NODES;
    size_t drow = brow + d;
    float4 ed4 = ((const float4*)ed)[drow];
    float dx = 0.f, dy = 0.f, dz = 0.f, dw = 0.f;
    {   // phase-1 rep 0 (always)
        int i = lane;
        float4 av = make_float4(0.f, 0.f, 0.f, 0.f);
        int sv = 0;
        if (i < n) {
            sv = colp[i];
            float4 e4 = ((const float4*)es)[brow + sv];
            float l, a0, a1, a2, a3;
            l = e4.x + ed4.x; l = l > 0.f ? l : 0.2f * l; EXP2(a0, l); dx += a0;
            l = e4.y + ed4.y; l = l > 0.f ? l : 0.2f * l; EXP2(a1, l); dy += a1;
            l = e4.z + ed4.z; l = l > 0.f ? l : 0.2f * l; EXP2(a2, l); dz += a2;
            l = e4.w + ed4.w; l = l > 0.f ? l : 0.2f * l; EXP2(a3, l); dw += a3;
            av = make_float4(a0, a1, a2, a3);
        }
        *(float4*)&evS[w][i][0] = av;
        colS[w][i] = sv;
    }
    if (n > 64) {   // phase-1 rep 1 (rare: max degree ~60)
        int i = lane + 64;
        float4 av = make_float4(0.f, 0.f, 0.f, 0.f);
        int sv = 0;
        if (i < n) {
            sv = colp[i];
            float4 e4 = ((const float4*)es)[brow + sv];
            float l, a0, a1, a2, a3;
            l = e4.x + ed4.x; l = l > 0.f ? l : 0.2f * l; EXP2(a0, l); dx += a0;
            l = e4.y + ed4.y; l = l > 0.f ? l : 0.2f * l; EXP2(a1, l); dy += a1;
            l = e4.z + ed4.z; l = l > 0.f ? l : 0.2f * l; EXP2(a2, l); dz += a2;
            l = e4.w + ed4.w; l = l > 0.f ? l : 0.2f * l; EXP2(a3, l); dw += a3;
            av = make_float4(a0, a1, a2, a3);
        }
        *(float4*)&evS[w][i][0] = av;
        colS[w][i] = sv;
    }
    WAVE_FENCE();
    float acc[8] = {};
    const __half* hbase = Hf + (brow << 7) + (c8 << 3);
    int nR = (n + 15) & ~15;
    for (int t = 0; t < nR; t += 16) {
        int t0 = t + eg, t1 = t0 + 4, t2 = t0 + 8, t3 = t0 + 12;
        float a0 = evS[w][t0][head], a1 = evS[w][t1][head];
        float a2 = evS[w][t2][head], a3 = evS[w][t3][head];
        int s0 = colS[w][t0], s1 = colS[w][t1], s2 = colS[w][t2], s3 = colS[w][t3];
        float4 r0 = *(const float4*)(hbase + ((size_t)s0 << 7));
        float4 r1 = *(const float4*)(hbase + ((size_t)s1 << 7));
        float4 r2 = *(const float4*)(hbase + ((size_t)s2 << 7));
        float4 r3 = *(const float4*)(hbase + ((size_t)s3 << 7));
        const unsigned* u0 = (const unsigned*)&r0;
        const unsigned* u1 = (const unsigned*)&r1;
        const unsigned* u2 = (const unsigned*)&r2;
        const unsigned* u3 = (const unsigned*)&r3;
        #pragma unroll
        for (int j = 0; j < 4; ++j) {
            FMA_MIX_LO(acc[2 * j],     u0[j], a0);
            FMA_MIX_HI(acc[2 * j + 1], u0[j], a0);
        }
        #pragma unroll
        for (int j = 0; j < 4; ++j) {
            FMA_MIX_LO(acc[2 * j],     u1[j], a1);
            FMA_MIX_HI(acc[2 * j + 1], u1[j], a1);
        }
        #pragma unroll
        for (int j = 0; j < 4; ++j) {
            FMA_MIX_LO(acc[2 * j],     u2[j], a2);
            FMA_MIX_HI(acc[2 * j + 1], u2[j], a2);
        }
        #pragma unroll
        for (int j = 0; j < 4; ++j) {
            FMA_MIX_LO(acc[2 * j],     u3[j], a3);
            FMA_MIX_HI(acc[2 * j + 1], u3[j], a3);
        }
    }
    #pragma unroll
    for (int off = 32; off; off >>= 1) {
        dx += __shfl_xor(dx, off);
        dy += __shfl_xor(dy, off);
        dz += __shfl_xor(dz, off);
        dw += __shfl_xor(dw, off);
    }
    float ix = 1.f / (dx + 1e-9f);
    float iy = 1.f / (dy + 1e-9f);
    float iz = 1.f / (dz + 1e-9f);
    float iw = 1.f / (dw + 1e-9f);
    float inv = (head & 2) ? ((head & 1) ? iw : iz) : ((head & 1) ? iy : ix);
    #pragma unroll
    for (int j = 0; j < 8; ++j) {
        acc[j] += __shfl_xor(acc[j], 16);
        acc[j] += __shfl_xor(acc[j], 32);
    }
    if (eg == 0) {
        float4 b0 = *(const float4*)(bias + 8 * c8);
        float4 b1 = *(const float4*)(bias + 8 * c8 + 4);
        float vals[8];
        vals[0] = fmaxf(acc[0] * inv + b0.x, 0.f);
        vals[1] = fmaxf(acc[1] * inv + b0.y, 0.f);
        vals[2] = fmaxf(acc[2] * inv + b0.z, 0.f);
        vals[3] = fmaxf(acc[3] * inv + b0.w, 0.f);
        vals[4] = fmaxf(acc[4] * inv + b1.x, 0.f);
        vals[5] = fmaxf(acc[5] * inv + b1.y, 0.f);
        vals[6] = fmaxf(acc[6] * inv + b1.z, 0.f);
        vals[7] = fmaxf(acc[7] * inv + b1.w, 0.f);
        __half2 o[4];
        #pragma unroll
        for (int j = 0; j < 4; ++j) o[j] = __floats2half2_rn(vals[2 * j], vals[2 * j + 1]);
        *(float4*)(outH + drow * 128 + c8 * 8) = *(float4*)o;
    }
}

// ---------------- layer-2 aggregation (rep-2 branch + exp2) ----------------
__global__ __launch_bounds__(512)
void agg2_kernel(const int* __restrict__ deg, const int* __restrict__ colPad,
                 const float* __restrict__ es, const float* __restrict__ ed,
                 const __half* __restrict__ Hf, const float* __restrict__ bias,
                 float* __restrict__ outF) {
    __shared__ float evS[8][MAXDEG];
    __shared__ int colS[8][MAXDEG];
    int blk = blockIdx.x;
    int b = blk & 7;
    int grp = blk >> 3;
    int w = threadIdx.x >> 6;
    int d = grp * 8 + w;
    int lane = threadIdx.x & 63;
    int eg = lane >> 2;
    int c8 = lane & 3;
    int n = deg[d];
    const int* colp = colPad + (d << 7);
    size_t brow = (size_t)b * N_NODES;
    size_t drow = brow + d;
    float edv = ed[drow];
    float den = 0.f;
    {
        int i = lane;
        float av = 0.f;
        int sv = 0;
        if (i < n) {
            sv = colp[i];
            float l = es[brow + sv] + edv;
            l = l > 0.f ? l : 0.2f * l;
            EXP2(av, l);
            den += av;
        }
        evS[w][i] = av;
        colS[w][i] = sv;
    }
    if (n > 64) {
        int i = lane + 64;
        float av = 0.f;
        int sv = 0;
        if (i < n) {
            sv = colp[i];
            float l = es[brow + sv] + edv;
            l = l > 0.f ? l : 0.2f * l;
            EXP2(av, l);
            den += av;
        }
        evS[w][i] = av;
        colS[w][i] = sv;
    }
    WAVE_FENCE();
    float acc[8] = {};
    const __half* hbase = Hf + (brow << 5) + (c8 << 3);
    int nR = (n + 31) & ~31;
    for (int t = 0; t < nR; t += 32) {
        int t0 = t + eg, t1 = t0 + 16;
        float a0 = evS[w][t0];
        float a1 = evS[w][t1];
        int s0 = colS[w][t0];
        int s1 = colS[w][t1];
        float4 r0 = *(const float4*)(hbase + ((size_t)s0 << 5));
        float4 r1 = *(const float4*)(hbase + ((size_t)s1 << 5));
        const unsigned* u0 = (const unsigned*)&r0;
        const unsigned* u1 = (const unsigned*)&r1;
        #pragma unroll
        for (int j = 0; j < 4; ++j) {
            FMA_MIX_LO(acc[2 * j],     u0[j], a0);
            FMA_MIX_HI(acc[2 * j + 1], u0[j], a0);
        }
        #pragma unroll
        for (int j = 0; j < 4; ++j) {
            FMA_MIX_LO(acc[2 * j],     u1[j], a1);
            FMA_MIX_HI(acc[2 * j + 1], u1[j], a1);
        }
    }
    #pragma unroll
    for (int off = 32; off; off >>= 1) den += __shfl_xor(den, off);
    float inv = 1.f / (den + 1e-9f);
    #pragma unroll
    for (int j = 0; j < 8; ++j) {
        acc[j] += __shfl_xor(acc[j], 4);
        acc[j] += __shfl_xor(acc[j], 8);
        acc[j] += __shfl_xor(acc[j], 16);
        acc[j] += __shfl_xor(acc[j], 32);
    }
    if (eg == 0) {
        float4 b0 = *(const float4*)(bias + 8 * c8);
        float4 b1 = *(const float4*)(bias + 8 * c8 + 4);
        float4 o0, o1;
        o0.x = acc[0] * inv + b0.x;
        o0.y = acc[1] * inv + b0.y;
        o0.z = acc[2] * inv + b0.z;
        o0.w = acc[3] * inv + b0.w;
        o1.x = acc[4] * inv + b1.x;
        o1.y = acc[5] * inv + b1.y;
        o1.z = acc[6] * inv + b1.z;
        o1.w = acc[7] * inv + b1.w;
        float* op = outF + drow * 32 + 8 * c8;
        *(float4*)op = o0;
        *(float4*)(op + 4) = o1;
    }
}

extern "C" void kernel_launch(void* const* d_in, const int* in_sizes, int n_in,
                              void* d_out, int out_size, void* d_ws, size_t ws_size,
                              hipStream_t stream) {
    const float* x    = (const float*)d_in[0];
    const int*   esrc = (const int*)d_in[1];
    const int*   edst = (const int*)d_in[2];
    const float* W1   = (const float*)d_in[3];
    const float* a1s  = (const float*)d_in[4];
    const float* a1d  = (const float*)d_in[5];
    const float* b1   = (const float*)d_in[6];
    const float* W2   = (const float*)d_in[7];
    const float* a2s  = (const float*)d_in[8];
    const float* a2d  = (const float*)d_in[9];
    const float* b2   = (const float*)d_in[10];
    float* out = (float*)d_out;
    const int E = in_sizes[1];
    const int rows = BATCH * N_NODES;  // 80000

    // workspace layout
    float* wsf = (float*)d_ws;
    __half* h1h   = (__half*)wsf;                       // rows*128 halfs
    float*  e1s   = wsf + (size_t)rows * 64;            // rows*4
    float*  e1d   = e1s + (size_t)rows * 4;             // rows*4
    __half* out1h = (__half*)(e1d + (size_t)rows * 4);  // rows*128 halfs
    int* deg      = (int*)((float*)out1h + (size_t)rows * 64);  // N
    int* colPad   = deg + N_NODES;                      // N*128
    __half* Wt1   = (__half*)(colPad + N_NODES * 128);  // 144*128 halfs
    __half* Wt2   = Wt1 + 144 * 128;                    // 48*128 halfs
    // layer 2 reuse
    __half* h2h = h1h;
    float*  e2s = e1s;
    float*  e2d = e1s + rows;

    const int TPB = 256;
    const int ZB = (N_NODES + TPB - 1) / TPB;
    const int PREPB = (144 * 128 + 48 * 128 + TPB - 1) / TPB;
    const int G1 = rows / 64;
    const int EB = (E + TPB - 1) / TPB;

    // ---------- 1: deg zero + weight prep ----------
    prep_kernel<<<ZB + PREPB, TPB, 0, stream>>>(
        ZB, deg, W1, a1s, a1d, W2, a2s, a2d, Wt1, Wt2);

    // ---------- 2: layer-1 GEMM (+logits) with edge-bucket build hidden under it --
    gemm1_build<<<G1 + EB, TPB, 0, stream>>>(
        x, Wt1, h1h, e1s, e1d, rows, G1, esrc, edst, deg, colPad, E);

    // ---------- 3: layer-1 aggregation ----------
    agg1_kernel<<<(N_NODES / 8) * BATCH, 512, 0, stream>>>(
        deg, colPad, e1s, e1d, h1h, b1, out1h);

    // ---------- 4: layer-2 GEMM (+logits) ----------
    gemm2_kernel<<<rows / 64, TPB, 0, stream>>>(
        out1h, Wt2, h2h, e2s, e2d, rows);

    // ---------- 5: layer-2 aggregation ----------
    agg2_kernel<<<(N_NODES / 8) * BATCH, 512, 0, stream>>>(
        deg, colPad, e2s, e2d, h2h, b2, out);
}